// Round 6
// baseline (130.705 us; speedup 1.0000x reference)
//
#include <hip/hip_runtime.h>
#include <hip/hip_cooperative_groups.h>

namespace cg = cooperative_groups;

// x[64][16][8192] f32, J=4, LEVELS=13, eps 1e-5.
// targets[j] = blockmean(2^(13-j)); inputs[j] = BN(blockmean(2^(13-j)) - blockmean(2^(14-j))), input[0]=BN(m0)
// Output [2][4][64][16][8192] f32.
// Single cooperative kernel, 1024 blocks (one per row), 256 threads.
// Phase 1: read x-row (NT), reduce to 15 block-mean stats, store to global stats table.
// grid.sync()
// Phase 2: wave j computes BN scale/shift for (j, c) from the stats table (L2-hot);
//          then pure store phase: 4 target rows + 4 input rows from register-held stats.

#define STATS_STRIDE 16
// stats row: [0]=m0, [1..2]=m1, [3..6]=m2, [7..14]=m3  (level j at base (1<<j)-1, count 1<<j)

typedef float f32x4 __attribute__((ext_vector_type(4)));

__global__ __launch_bounds__(256) void fused_kernel(const float* __restrict__ x,
                                                    const float* __restrict__ gamma,
                                                    const float* __restrict__ beta,
                                                    float* __restrict__ stats,
                                                    f32x4* __restrict__ out) {
    int row = blockIdx.x;                 // 0..1023  (b=row>>4, c=row&15)
    int c = row & 15;
    int t = threadIdx.x;                  // 0..255
    int lane = t & 63, wave = t >> 6;

    // ---- phase 1: row stats ----
    const f32x4* xr = reinterpret_cast<const f32x4*>(x) + (size_t)row * 2048;
    float s[8];
#pragma unroll
    for (int k = 0; k < 8; ++k) {
        f32x4 v = __builtin_nontemporal_load(&xr[t + 256 * k]);  // iter k = 1024-block k
        s[k] = (v.x + v.y) + (v.z + v.w);
    }
    __shared__ float red[8][4];
    __shared__ float sb[16];
#pragma unroll
    for (int k = 0; k < 8; ++k) {
        float v = s[k];
#pragma unroll
        for (int off = 32; off; off >>= 1) v += __shfl_down(v, off, 64);
        if (lane == 0) red[k][wave] = v;
    }
    __syncthreads();
    if (t < 8) sb[7 + t] = (red[t][0] + red[t][1] + red[t][2] + red[t][3]) * (1.0f / 1024.0f);
    __syncthreads();
    if (t == 0) {
        float m2[4], m1[2];
#pragma unroll
        for (int k = 0; k < 4; ++k) m2[k] = 0.5f * (sb[7 + 2 * k] + sb[7 + 2 * k + 1]);
        m1[0] = 0.5f * (m2[0] + m2[1]);
        m1[1] = 0.5f * (m2[2] + m2[3]);
        sb[0] = 0.5f * (m1[0] + m1[1]);
        sb[1] = m1[0]; sb[2] = m1[1];
        sb[3] = m2[0]; sb[4] = m2[1]; sb[5] = m2[2]; sb[6] = m2[3];
    }
    __syncthreads();
    if (t < 15) stats[(size_t)row * STATS_STRIDE + t] = sb[t];
    float rv[15];
#pragma unroll
    for (int k = 0; k < 15; ++k) rv[k] = sb[k];

    cg::this_grid().sync();

    // ---- phase 2a: BN scale/shift; wave j handles level j for this block's c ----
    __shared__ float ss[4][2];
    {
        int j = wave;
        const float* sp = stats + (size_t)((lane << 4) + c) * STATS_STRIDE;
        float sum = 0.f, sum2 = 0.f;
        if (j == 0) {
            float d = sp[0];
            sum = d; sum2 = d * d;
        } else {
            int base = (1 << j) - 1, pb = (1 << (j - 1)) - 1;
            for (int k = 0; k < (1 << j); ++k) {
                float d = sp[base + k] - sp[pb + (k >> 1)];
                sum += d; sum2 += d * d;
            }
        }
        float B = (float)(8192 >> j);
        sum *= B; sum2 *= B;
#pragma unroll
        for (int off = 32; off; off >>= 1) {
            sum  += __shfl_down(sum, off, 64);
            sum2 += __shfl_down(sum2, off, 64);
        }
        if (lane == 0) {
            const float N = 64.0f * 8192.0f;
            float mean = sum / N;
            float var = sum2 / N - mean * mean;
            float inv = rsqrtf(var + 1e-5f);
            float sc = gamma[(j << 4) + c] * inv;
            ss[j][0] = sc;
            ss[j][1] = beta[(j << 4) + c] - mean * sc;
        }
    }
    __syncthreads();

    // ---- phase 2b: pure store phase (8 rows x 32 KB) ----
#pragma unroll
    for (int j = 0; j < 4; ++j) {         // targets (part=1)
        f32x4* orow = out + ((size_t)(4 + j) * 1024 + row) * 2048;
        int sh = 3 - j;
#pragma unroll
        for (int i = 0; i < 8; ++i) {
            float v = rv[(1 << j) - 1 + (i >> sh)];
            f32x4 q = {v, v, v, v};
            orow[t + (i << 8)] = q;
        }
    }
#pragma unroll
    for (int j = 0; j < 4; ++j) {         // inputs (part=0), BN applied
        float sc = ss[j][0], sh0 = ss[j][1];
        int shr = 3 - j;
        f32x4* orow = out + ((size_t)j * 1024 + row) * 2048;
#pragma unroll
        for (int i = 0; i < 8; ++i) {
            int run = i >> shr;           // uniform per i
            float mj = rv[(1 << j) - 1 + run];
            float d = (j == 0) ? mj : mj - rv[(1 << (j - 1)) - 1 + (run >> 1)];
            float v = d * sc + sh0;
            f32x4 q = {v, v, v, v};
            orow[t + (i << 8)] = q;
        }
    }
}

extern "C" void kernel_launch(void* const* d_in, const int* in_sizes, int n_in,
                              void* d_out, int out_size, void* d_ws, size_t ws_size,
                              hipStream_t stream) {
    const float* x     = (const float*)d_in[0];
    const float* gamma = (const float*)d_in[1];
    const float* beta  = (const float*)d_in[2];
    f32x4* out = (f32x4*)d_out;
    float* stats = (float*)d_ws;          // 1024*16 floats = 64 KiB

    void* args[] = {(void*)&x, (void*)&gamma, (void*)&beta, (void*)&stats, (void*)&out};
    hipLaunchCooperativeKernel((const void*)fused_kernel, dim3(1024), dim3(256), args, 0, stream);
}

// Round 7
// 55.249 us; speedup vs baseline: 2.3657x; 2.3657x over previous
//
#include <hip/hip_runtime.h>

// x[64][16][8192] f32, J=4, LEVELS=13, eps 1e-5.
// targets[j] = blockmean(2^(13-j)); inputs[j] = BN(blockmean(2^(13-j)) - blockmean(2^(14-j))), input[0]=BN(m0)
// Output [2][4][64][16][8192] f32.
// Kernel 1 (pure read): per row, reduce x-row to 15 block-mean stats -> 64 KB table.
// Kernel 2 (pure write): per row, wave j computes BN(j,c) from L2-hot table, then
//                        8 x 32 KB store-only row writes (268 MB total).

#define STATS_STRIDE 16
// stats row: [0]=m0, [1..2]=m1, [3..6]=m2, [7..14]=m3  (level j at base (1<<j)-1, count 1<<j)

typedef float f32x4 __attribute__((ext_vector_type(4)));

__global__ __launch_bounds__(256) void row_stats_kernel(const float* __restrict__ x,
                                                        float* __restrict__ stats) {
    int row = blockIdx.x;                 // 0..1023
    int t = threadIdx.x;                  // 0..255
    int lane = t & 63, wave = t >> 6;
    const f32x4* xr = reinterpret_cast<const f32x4*>(x) + (size_t)row * 2048;
    float s[8];
#pragma unroll
    for (int k = 0; k < 8; ++k) {
        f32x4 v = __builtin_nontemporal_load(&xr[t + 256 * k]);  // iter k = 1024-block k
        s[k] = (v.x + v.y) + (v.z + v.w);
    }
    __shared__ float red[8][4];
    __shared__ float sb[16];
#pragma unroll
    for (int k = 0; k < 8; ++k) {
        float v = s[k];
#pragma unroll
        for (int off = 32; off; off >>= 1) v += __shfl_down(v, off, 64);
        if (lane == 0) red[k][wave] = v;
    }
    __syncthreads();
    if (t < 8) sb[7 + t] = (red[t][0] + red[t][1] + red[t][2] + red[t][3]) * (1.0f / 1024.0f);
    __syncthreads();
    if (t == 0) {
        float m2[4], m1[2];
#pragma unroll
        for (int k = 0; k < 4; ++k) m2[k] = 0.5f * (sb[7 + 2 * k] + sb[7 + 2 * k + 1]);
        m1[0] = 0.5f * (m2[0] + m2[1]);
        m1[1] = 0.5f * (m2[2] + m2[3]);
        sb[0] = 0.5f * (m1[0] + m1[1]);
        sb[1] = m1[0]; sb[2] = m1[1];
        sb[3] = m2[0]; sb[4] = m2[1]; sb[5] = m2[2]; sb[6] = m2[3];
    }
    __syncthreads();
    if (t < 15) stats[(size_t)row * STATS_STRIDE + t] = sb[t];
}

__global__ __launch_bounds__(256) void write_all_kernel(const float* __restrict__ stats,
                                                        const float* __restrict__ gamma,
                                                        const float* __restrict__ beta,
                                                        f32x4* __restrict__ out) {
    int row = blockIdx.x;                 // 0..1023  (b=row>>4, c=row&15)
    int c = row & 15;
    int t = threadIdx.x;
    int lane = t & 63, wave = t >> 6;

    // BN scale/shift: wave j reduces over the 64 batch rows of channel c (L2-hot table)
    __shared__ float ss[4][2];
    {
        int j = wave;
        const float* sp = stats + (size_t)((lane << 4) + c) * STATS_STRIDE;
        float sum = 0.f, sum2 = 0.f;
        if (j == 0) {
            float d = sp[0];
            sum = d; sum2 = d * d;
        } else {
            int base = (1 << j) - 1, pb = (1 << (j - 1)) - 1;
            for (int k = 0; k < (1 << j); ++k) {
                float d = sp[base + k] - sp[pb + (k >> 1)];
                sum += d; sum2 += d * d;
            }
        }
        float B = (float)(8192 >> j);
        sum *= B; sum2 *= B;
#pragma unroll
        for (int off = 32; off; off >>= 1) {
            sum  += __shfl_down(sum, off, 64);
            sum2 += __shfl_down(sum2, off, 64);
        }
        if (lane == 0) {
            const float N = 64.0f * 8192.0f;
            float mean = sum / N;
            float var = sum2 / N - mean * mean;
            float inv = rsqrtf(var + 1e-5f);
            float sc = gamma[(j << 4) + c] * inv;
            ss[j][0] = sc;
            ss[j][1] = beta[(j << 4) + c] - mean * sc;
        }
    }
    // own row's 15 run values (L2-hot, one 64B line)
    float rv[15];
    {
        const float* sp = stats + (size_t)row * STATS_STRIDE;
#pragma unroll
        for (int k = 0; k < 15; ++k) rv[k] = sp[k];
    }
    __syncthreads();

    // pure store phase: 8 rows x 32 KB
#pragma unroll
    for (int j = 0; j < 4; ++j) {         // targets (part=1)
        f32x4* orow = out + ((size_t)(4 + j) * 1024 + row) * 2048;
        int sh = 3 - j;
#pragma unroll
        for (int i = 0; i < 8; ++i) {
            float v = rv[(1 << j) - 1 + (i >> sh)];
            f32x4 q = {v, v, v, v};
            orow[t + (i << 8)] = q;
        }
    }
#pragma unroll
    for (int j = 0; j < 4; ++j) {         // inputs (part=0), BN applied
        float sc = ss[j][0], sh0 = ss[j][1];
        int shr = 3 - j;
        f32x4* orow = out + ((size_t)j * 1024 + row) * 2048;
#pragma unroll
        for (int i = 0; i < 8; ++i) {
            int run = i >> shr;           // uniform per i
            float mj = rv[(1 << j) - 1 + run];
            float d = (j == 0) ? mj : mj - rv[(1 << (j - 1)) - 1 + (run >> 1)];
            float v = d * sc + sh0;
            f32x4 q = {v, v, v, v};
            orow[t + (i << 8)] = q;
        }
    }
}

extern "C" void kernel_launch(void* const* d_in, const int* in_sizes, int n_in,
                              void* d_out, int out_size, void* d_ws, size_t ws_size,
                              hipStream_t stream) {
    const float* x     = (const float*)d_in[0];
    const float* gamma = (const float*)d_in[1];
    const float* beta  = (const float*)d_in[2];
    f32x4* out = (f32x4*)d_out;
    float* stats = (float*)d_ws;          // 1024*16 floats = 64 KiB

    row_stats_kernel<<<1024, 256, 0, stream>>>(x, stats);
    write_all_kernel<<<1024, 256, 0, stream>>>(stats, gamma, beta, out);
}